// Round 18
// baseline (302.834 us; speedup 1.0000x reference)
//
#include <hip/hip_runtime.h>

#define NN   100000
#define NE   500000
#define DD   128
#define HH   4
#define HIDD 512
#define EPSF 1e-5f

typedef __bf16 bf16x8 __attribute__((ext_vector_type(8)));
typedef float  f32x4  __attribute__((ext_vector_type(4)));
typedef unsigned short u16x8 __attribute__((ext_vector_type(8)));

__device__ __forceinline__ unsigned short f2b(float f) {
  unsigned u = __float_as_uint(f);
  unsigned r = (u + 0x7FFFu + ((u >> 16) & 1)) >> 16;
  return (unsigned short)r;
}
__device__ __forceinline__ float b2f(unsigned short s) {
  return __uint_as_float(((unsigned)s) << 16);
}

#define GLOAD16(ldsp, gp) __builtin_amdgcn_global_load_lds(                      \
    (const __attribute__((address_space(1))) void*)(gp),                         \
    (__attribute__((address_space(3))) void*)(ldsp), 16, 0, 0)

// stage a 128x128 bf16 tile: linear LDS dest, inverse-swizzled global source.
// read side uses 16B slot (c16 ^ (row&15)).
template <int NT>
__device__ __forceinline__ void stage_tile(unsigned short* lds, const unsigned short* g,
                                           int ldg, int t) {
  const int w = t >> 6, l = t & 63;
#pragma unroll
  for (int i = 0; i < 2048 / NT; i++) {
    const int chunk0 = i * NT + w * 64;   // wave-uniform
    const int chunk = chunk0 + l;
    const int row = chunk >> 4, c16 = chunk & 15;
    const int gslot = c16 ^ (row & 15);
    GLOAD16(lds + (size_t)chunk0 * 8, g + (size_t)row * ldg + gslot * 8);
  }
}

// weight casts + bias pack + cnt zeroing in ONE launch (600 blocks)
__global__ void k_castw(const float* __restrict__ Wq, const float* __restrict__ Wk,
                        const float* __restrict__ Wv, const float* __restrict__ Wsk,
                        const float* __restrict__ Wo, const float* __restrict__ W1,
                        const float* __restrict__ W2,
                        const float* __restrict__ bq, const float* __restrict__ bk,
                        const float* __restrict__ bv, const float* __restrict__ bs,
                        unsigned short* __restrict__ Wqkvs, unsigned short* __restrict__ Wob,
                        unsigned short* __restrict__ W1b, unsigned short* __restrict__ W2b,
                        float* __restrict__ bias512, int* __restrict__ cnt) {
  int i = blockIdx.x * 256 + threadIdx.x;
  if (i < 53248) {
    int e = i * 4;
    const float* src; unsigned short* dst; int off;
    if (e < 65536) {
      int seg = e >> 14;
      const float* s4[4] = {Wq, Wk, Wv, Wsk};
      src = s4[seg]; dst = Wqkvs + (seg << 14); off = e & 16383;
    } else if (e < 81920) { src = Wo;  dst = Wob; off = e - 65536; }
    else if (e < 147456)  { src = W1;  dst = W1b; off = e - 81920; }
    else                  { src = W2;  dst = W2b; off = e - 147456; }
    float4 v = *(const float4*)&src[off];
    ushort4 o; o.x = f2b(v.x); o.y = f2b(v.y); o.z = f2b(v.z); o.w = f2b(v.w);
    *(ushort4*)&dst[off] = o;
  } else if (i < 53376) {
    int b4 = (i - 53248) * 4;
    const float* srcs[4] = {bq, bk, bv, bs};
#pragma unroll
    for (int j = 0; j < 4; j++) {
      int idx = b4 + j;
      bias512[idx] = srcs[idx >> 7][idx & 127];
    }
  } else if (i >= 53504) {
    int idx = i - 53504;
    if (idx < NN) cnt[idx] = 0;
  }
}

// ---------------- CSR build ----------------
__global__ void k_count(const int* __restrict__ ei, int* __restrict__ cnt) {
  int e = blockIdx.x * 256 + threadIdx.x;
  if (e < NE) atomicAdd(&cnt[ei[NE + e]], 1);
}
__global__ void k_scan1(const int* __restrict__ cnt, int* __restrict__ rowptr, int* __restrict__ part) {
  __shared__ int sh[256];
  int i = blockIdx.x * 256 + threadIdx.x;
  int v = (i < NN) ? cnt[i] : 0;
  sh[threadIdx.x] = v; __syncthreads();
  for (int off = 1; off < 256; off <<= 1) {
    int t = (threadIdx.x >= off) ? sh[threadIdx.x - off] : 0;
    __syncthreads();
    sh[threadIdx.x] += t;
    __syncthreads();
  }
  if (i < NN) rowptr[i] = sh[threadIdx.x] - v;  // exclusive
  if (threadIdx.x == 255) part[blockIdx.x] = sh[255];
}
__global__ void k_scan2(const int* __restrict__ part, int* __restrict__ partx) {
  __shared__ int sh[512];
  int t = threadIdx.x;
  int v = (t < 391) ? part[t] : 0;
  sh[t] = v; __syncthreads();
  for (int off = 1; off < 512; off <<= 1) {
    int u = (t >= off) ? sh[t - off] : 0;
    __syncthreads();
    sh[t] += u;
    __syncthreads();
  }
  partx[t] = sh[t] - v;
}
__global__ void k_scan3(int* __restrict__ rowptr, const int* __restrict__ partx, int* __restrict__ cnt) {
  int i = blockIdx.x * 256 + threadIdx.x;
  if (i < NN) {
    int r = rowptr[i] + partx[i >> 8];
    rowptr[i] = r;
    cnt[i] = r;
  }
  if (i == 0) rowptr[NN] = NE;
}
__global__ void k_scatter(const int* __restrict__ ei, int* __restrict__ cnt, int* __restrict__ csr_src) {
  int e = blockIdx.x * 256 + threadIdx.x;
  if (e >= NE) return;
  int d = ei[NE + e];
  int pos = atomicAdd(&cnt[d], 1);
  csr_src[pos] = ei[e];
}

#define LOADA(dst, Aptr, LDA_)                                                   \
  _Pragma("unroll") for (int ks = 0; ks < 4; ks++)                               \
    _Pragma("unroll") for (int rt = 0; rt < 2; rt++) {                           \
      const int row_ = n0 + rt * 16 + lq;                                        \
      bf16x8 zz = {};                                                            \
      dst[ks][rt] = (row_ < NN)                                                  \
          ? *(const bf16x8*)&(Aptr)[(size_t)row_ * (LDA_) + ks * 32 + hq * 8]    \
          : zz;                                                                  \
    }

#define LOADA_F32(dst, Xp)                                                       \
  _Pragma("unroll") for (int ks = 0; ks < 4; ks++)                               \
    _Pragma("unroll") for (int rt = 0; rt < 2; rt++) {                           \
      const int row_ = n0 + rt * 16 + lq;                                        \
      u16x8 tmp = {};                                                            \
      if (row_ < NN) {                                                           \
        const float* p = (Xp) + (size_t)row_ * 128 + ks * 32 + hq * 8;           \
        float4 f0 = *(const float4*)p, f1 = *(const float4*)(p + 4);             \
        tmp[0]=f2b(f0.x); tmp[1]=f2b(f0.y); tmp[2]=f2b(f0.z); tmp[3]=f2b(f0.w);  \
        tmp[4]=f2b(f1.x); tmp[5]=f2b(f1.y); tmp[6]=f2b(f1.z); tmp[7]=f2b(f1.w);  \
      }                                                                          \
      dst[ks][rt] = *(bf16x8*)&tmp;                                              \
    }

#define MFMA_PHASE(WS, AF, ACC)                                                  \
  _Pragma("unroll") for (int ks = 0; ks < 4; ks++) {                             \
    bf16x8 bb[8];                                                                \
    const int c16_ = ks * 4 + hq;                                                \
    _Pragma("unroll") for (int ct = 0; ct < 8; ct++) {                           \
      const int row_ = ct * 16 + lq;                                             \
      bb[ct] = *(const bf16x8*)&WS[row_ * 128 + ((c16_ ^ lq) * 8)];              \
    }                                                                            \
    _Pragma("unroll") for (int rt = 0; rt < 2; rt++)                             \
      _Pragma("unroll") for (int ct = 0; ct < 8; ct++)                           \
        ACC[rt][ct] = __builtin_amdgcn_mfma_f32_16x16x32_bf16(bb[ct], AF[ks][rt], ACC[rt][ct], 0, 0, 0); \
  }

// ---------------- qkvs: x fp32 -> qkvsb bf16 [N,512]; 256 rows/block, dbuf W ----------------
__global__ __launch_bounds__(512, 2) void k_qkvs(const float* __restrict__ x,
                                                 const unsigned short* __restrict__ W,
                                                 const float* __restrict__ bias,
                                                 unsigned short* __restrict__ outB) {
  __shared__ __align__(16) unsigned short WsA[128 * 128];
  __shared__ __align__(16) unsigned short WsB[128 * 128];
  const int t = threadIdx.x;
  const int w = t >> 6, l = t & 63;
  const int n0 = blockIdx.x * 256 + w * 32;
  const int lq = l & 15, hq = l >> 4;

  bf16x8 af[4][2];
  LOADA_F32(af, x);
  stage_tile<512>(WsA, W, 128, t);
  __syncthreads();
#pragma unroll
  for (int cg = 0; cg < 4; ++cg) {
    unsigned short* cur = (cg & 1) ? WsB : WsA;
    unsigned short* nxt = (cg & 1) ? WsA : WsB;
    if (cg < 3) stage_tile<512>(nxt, W + (size_t)(cg + 1) * 128 * 128, 128, t);
    f32x4 acc[2][8] = {};
    MFMA_PHASE(cur, af, acc)
#pragma unroll
    for (int rt = 0; rt < 2; rt++) {
      const int row = n0 + rt * 16 + lq;
      if (row < NN) {
#pragma unroll
        for (int ct = 0; ct < 8; ct++) {
          const int col = cg * 128 + ct * 16 + hq * 4;
          const float4 bs = *(const float4*)&bias[col];
          ushort4 o;
          o.x = f2b(acc[rt][ct][0] + bs.x);
          o.y = f2b(acc[rt][ct][1] + bs.y);
          o.z = f2b(acc[rt][ct][2] + bs.z);
          o.w = f2b(acc[rt][ct][3] + bs.w);
          *(ushort4*)&outB[(size_t)row * 512 + col] = o;
        }
      }
    }
    if (cg < 3) __syncthreads();
  }
}

// ---------------- out-proj GEMM (K=128) + x residual (fp32) + LN1 -> out2b bf16 ----------------
__global__ __launch_bounds__(256, 4) void k_gemm_ln1(const unsigned short* __restrict__ A,
                                                     const float* __restrict__ x,
                                                     const unsigned short* __restrict__ W,
                                                     const float* __restrict__ bias,
                                                     const float* __restrict__ lw,
                                                     const float* __restrict__ lb,
                                                     unsigned short* __restrict__ outB) {
  __shared__ __align__(16) unsigned short Ws[128 * 128];
  const int t = threadIdx.x;
  const int w = t >> 6, l = t & 63;
  const int n0 = blockIdx.x * 128 + w * 32;
  const int lq = l & 15, hq = l >> 4;

  bf16x8 af[4][2];
  LOADA(af, A, 512);
  stage_tile<256>(Ws, W, 128, t);
  __syncthreads();
  f32x4 acc[2][8] = {};
  MFMA_PHASE(Ws, af, acc)
#pragma unroll
  for (int rt = 0; rt < 2; rt++) {
    const int row = n0 + rt * 16 + lq;
#pragma unroll
    for (int ct = 0; ct < 8; ct++) {
      const int col = ct * 16 + hq * 4;
      const float4 bs = *(const float4*)&bias[col];
      float4 rv = make_float4(0.f, 0.f, 0.f, 0.f);
      if (row < NN) rv = *(const float4*)&x[(size_t)row * DD + col];
      acc[rt][ct][0] += bs.x + rv.x;
      acc[rt][ct][1] += bs.y + rv.y;
      acc[rt][ct][2] += bs.z + rv.z;
      acc[rt][ct][3] += bs.w + rv.w;
    }
    float s = 0.f;
#pragma unroll
    for (int ct = 0; ct < 8; ct++)
#pragma unroll
      for (int j = 0; j < 4; j++) s += acc[rt][ct][j];
    s += __shfl_xor(s, 16, 64); s += __shfl_xor(s, 32, 64);
    const float mu = s * (1.f / 128.f);
    float vs = 0.f;
#pragma unroll
    for (int ct = 0; ct < 8; ct++)
#pragma unroll
      for (int j = 0; j < 4; j++) { float d = acc[rt][ct][j] - mu; vs += d * d; }
    vs += __shfl_xor(vs, 16, 64); vs += __shfl_xor(vs, 32, 64);
    const float rs = rsqrtf(vs * (1.f / 128.f) + EPSF);
    if (row < NN) {
#pragma unroll
      for (int ct = 0; ct < 8; ct++) {
        const int col = ct * 16 + hq * 4;
        const float4 lw4 = *(const float4*)&lw[col];
        const float4 lb4 = *(const float4*)&lb[col];
        ushort4 o;
        o.x = f2b((acc[rt][ct][0] - mu) * rs * lw4.x + lb4.x);
        o.y = f2b((acc[rt][ct][1] - mu) * rs * lw4.y + lb4.y);
        o.z = f2b((acc[rt][ct][2] - mu) * rs * lw4.z + lb4.z);
        o.w = f2b((acc[rt][ct][3] - mu) * rs * lw4.w + lb4.w);
        *(ushort4*)&outB[(size_t)row * DD + col] = o;
      }
    }
  }
}

// ---------------- fused FFN (R14-exact structure, (256,2)); W2 stage hidden under Hs-write ----------------
__global__ __launch_bounds__(256, 2) void k_ffn_fused(const unsigned short* __restrict__ A,
                                                      const unsigned short* __restrict__ W1,
                                                      const float* __restrict__ b1,
                                                      const unsigned short* __restrict__ W2,
                                                      const float* __restrict__ b2,
                                                      const float* __restrict__ lw,
                                                      const float* __restrict__ lb,
                                                      float* __restrict__ outF) {
  __shared__ __align__(16) unsigned short Ws[128 * 128];
  __shared__ __align__(16) unsigned short Hs[128 * 128];
  const int t = threadIdx.x;
  const int w = t >> 6, l = t & 63;
  const int n0 = blockIdx.x * 128 + w * 32;
  const int lq = l & 15, hq = l >> 4;
  const int lrow = w * 32;

  bf16x8 af[4][2];
  LOADA(af, A, 128);

  f32x4 acc2[2][8] = {};
#pragma unroll 1
  for (int cg = 0; cg < 4; ++cg) {
    if (cg) __syncthreads();              // prev MFMA2 done reading Ws & Hs
    stage_tile<256>(Ws, W1 + (size_t)cg * 128 * 128, 128, t);
    __syncthreads();                      // W1[cg] ready
    f32x4 acc1[2][8] = {};
    MFMA_PHASE(Ws, af, acc1)
    __syncthreads();                      // all W1 reads done
    stage_tile<256>(Ws, W2 + (size_t)cg * 128, 512, t);  // latency hides under Hs-write
#pragma unroll
    for (int rt = 0; rt < 2; rt++) {
      const int row = lrow + rt * 16 + lq;
#pragma unroll
      for (int ct = 0; ct < 8; ct++) {
        const int col = ct * 16 + hq * 4;
        const float4 bs = *(const float4*)&b1[cg * 128 + col];
        ushort4 o;
        o.x = f2b(fmaxf(acc1[rt][ct][0] + bs.x, 0.f));
        o.y = f2b(fmaxf(acc1[rt][ct][1] + bs.y, 0.f));
        o.z = f2b(fmaxf(acc1[rt][ct][2] + bs.z, 0.f));
        o.w = f2b(fmaxf(acc1[rt][ct][3] + bs.w, 0.f));
        *(ushort4*)&Hs[row * 128 + (((col >> 3) ^ lq) * 8) + (col & 7)] = o;
      }
    }
    __syncthreads();                      // W2 ready + Hs visible
#pragma unroll
    for (int ks = 0; ks < 4; ks++) {
      bf16x8 bb[8];
      const int c16_ = ks * 4 + hq;
#pragma unroll
      for (int ct = 0; ct < 8; ct++) {
        const int row_ = ct * 16 + lq;
        bb[ct] = *(const bf16x8*)&Ws[row_ * 128 + ((c16_ ^ lq) * 8)];
      }
      bf16x8 h[2];
#pragma unroll
      for (int rt = 0; rt < 2; rt++)
        h[rt] = *(const bf16x8*)&Hs[(lrow + rt * 16 + lq) * 128 + ((c16_ ^ lq) * 8)];
#pragma unroll
      for (int rt = 0; rt < 2; rt++)
#pragma unroll
        for (int ct = 0; ct < 8; ct++)
          acc2[rt][ct] = __builtin_amdgcn_mfma_f32_16x16x32_bf16(bb[ct], h[rt], acc2[rt][ct], 0, 0, 0);
    }
  }

  // epilogue: + b2 + out2b residual + LN2 -> fp32 d_out
#pragma unroll
  for (int rt = 0; rt < 2; rt++) {
    const int row = n0 + rt * 16 + lq;
#pragma unroll
    for (int ct = 0; ct < 8; ct++) {
      const int col = ct * 16 + hq * 4;
      const float4 bs = *(const float4*)&b2[col];
      ushort4 rv = make_ushort4(0, 0, 0, 0);
      if (row < NN) rv = *(const ushort4*)&A[(size_t)row * DD + col];
      acc2[rt][ct][0] += bs.x + b2f(rv.x);
      acc2[rt][ct][1] += bs.y + b2f(rv.y);
      acc2[rt][ct][2] += bs.z + b2f(rv.z);
      acc2[rt][ct][3] += bs.w + b2f(rv.w);
    }
    float s = 0.f;
#pragma unroll
    for (int ct = 0; ct < 8; ct++)
#pragma unroll
      for (int j = 0; j < 4; j++) s += acc2[rt][ct][j];
    s += __shfl_xor(s, 16, 64); s += __shfl_xor(s, 32, 64);
    const float mu = s * (1.f / 128.f);
    float vs = 0.f;
#pragma unroll
    for (int ct = 0; ct < 8; ct++)
#pragma unroll
      for (int j = 0; j < 4; j++) { float d = acc2[rt][ct][j] - mu; vs += d * d; }
    vs += __shfl_xor(vs, 16, 64); vs += __shfl_xor(vs, 32, 64);
    const float rs = rsqrtf(vs * (1.f / 128.f) + EPSF);
    if (row < NN) {
#pragma unroll
      for (int ct = 0; ct < 8; ct++) {
        const int col = ct * 16 + hq * 4;
        const float4 lw4 = *(const float4*)&lw[col];
        const float4 lb4 = *(const float4*)&lb[col];
        float4 o;
        o.x = (acc2[rt][ct][0] - mu) * rs * lw4.x + lb4.x;
        o.y = (acc2[rt][ct][1] - mu) * rs * lw4.y + lb4.y;
        o.z = (acc2[rt][ct][2] - mu) * rs * lw4.z + lb4.z;
        o.w = (acc2[rt][ct][3] - mu) * rs * lw4.w + lb4.w;
        *(float4*)&outF[(size_t)row * DD + col] = o;
      }
    }
  }
}

// ---------------- single-pass fused attention: one 16B load per edge, unroll 8 ----------------
__global__ __launch_bounds__(256) void k_attn(const int* __restrict__ csr_src,
                                              const int* __restrict__ rowptr,
                                              unsigned short* qkvsb) {
  const int l = threadIdx.x & 31;
  const int node = blockIdx.x * 8 + (threadIdx.x >> 5);  // grid exact: 12500*8
  const int row0 = rowptr[node], row1 = rowptr[node + 1];
  const bool isV = l >= 16;
  const int l16 = l & 15;
  const int bidx = (l16 >> 2) << 2;
  float qf[8];
  {
    u16x8 qv = *(const u16x8*)&qkvsb[(size_t)node * 512 + l16 * 8];
#pragma unroll
    for (int i = 0; i < 8; i++) qf[i] = b2f(qv[i]);
  }
  float acc[8] = {};
  float z = 0.f;
  int p = row0;
  for (; p + 8 <= row1; p += 8) {
    u16x8 r[8];
#pragma unroll
    for (int u = 0; u < 8; u++) {
      int s = csr_src[p + u];
      r[u] = *(const u16x8*)&qkvsb[(size_t)s * 512 + 128 + l * 8];
    }
    float d[8];
#pragma unroll
    for (int u = 0; u < 8; u++) {
      float dd = 0.f;
#pragma unroll
      for (int i = 0; i < 8; i++) dd += qf[i] * b2f(r[u][i]);
      d[u] = dd;
    }
#pragma unroll
    for (int u = 0; u < 8; u++) d[u] += __shfl_xor(d[u], 1, 32);
#pragma unroll
    for (int u = 0; u < 8; u++) d[u] += __shfl_xor(d[u], 2, 32);
    float e[8];
#pragma unroll
    for (int u = 0; u < 8; u++) e[u] = __expf(d[u] * 0.17677669529663687f);
    float wq[8];
#pragma unroll
    for (int u = 0; u < 8; u++) wq[u] = __shfl(e[u], bidx, 32);
    if (isV) {
#pragma unroll
      for (int i = 0; i < 8; i++) {
        float a = acc[i];
#pragma unroll
        for (int u = 0; u < 8; u++) a += wq[u] * b2f(r[u][i]);
        acc[i] = a;
      }
    } else {
#pragma unroll
      for (int u = 0; u < 8; u++) z += e[u];
    }
  }
  for (; p < row1; ++p) {
    int s = csr_src[p];
    u16x8 r0 = *(const u16x8*)&qkvsb[(size_t)s * 512 + 128 + l * 8];
    float d0 = 0.f;
#pragma unroll
    for (int i = 0; i < 8; i++) d0 += qf[i] * b2f(r0[i]);
    d0 += __shfl_xor(d0, 1, 32);
    d0 += __shfl_xor(d0, 2, 32);
    float e0 = __expf(d0 * 0.17677669529663687f);
    float w0 = __shfl(e0, bidx, 32);
    if (isV) {
#pragma unroll
      for (int i = 0; i < 8; i++) acc[i] += w0 * b2f(r0[i]);
    } else {
      z += e0;
    }
  }
  float zz = __shfl(z, bidx, 32);
  const float rz = (zz > 0.f) ? (1.f / zz) : 0.f;
  if (isV) {
    u16x8 su = *(const u16x8*)&qkvsb[(size_t)node * 512 + 384 + l16 * 8];
    u16x8 o;
#pragma unroll
    for (int i = 0; i < 8; i++) o[i] = f2b(b2f(su[i]) + acc[i] * rz);
    *(u16x8*)&qkvsb[(size_t)node * 512 + 384 + l16 * 8] = o;
  }
}

extern "C" void kernel_launch(void* const* d_in, const int* in_sizes, int n_in,
                              void* d_out, int out_size, void* d_ws, size_t ws_size,
                              hipStream_t stream) {
  const float* x   = (const float*)d_in[0];
  const int*   ei  = (const int*)d_in[1];
  const float* Wq  = (const float*)d_in[2];
  const float* bq  = (const float*)d_in[3];
  const float* Wk  = (const float*)d_in[4];
  const float* bk  = (const float*)d_in[5];
  const float* Wv  = (const float*)d_in[6];
  const float* bv  = (const float*)d_in[7];
  const float* Wsk = (const float*)d_in[8];
  const float* bsk = (const float*)d_in[9];
  const float* Wo  = (const float*)d_in[10];
  const float* bo  = (const float*)d_in[11];
  const float* l1w = (const float*)d_in[12];
  const float* l1b = (const float*)d_in[13];
  const float* l2w = (const float*)d_in[14];
  const float* l2b = (const float*)d_in[15];
  const float* W1  = (const float*)d_in[16];
  const float* b1  = (const float*)d_in[17];
  const float* W2  = (const float*)d_in[18];
  const float* b2  = (const float*)d_in[19];

  unsigned short* wsu = (unsigned short*)d_ws;
  unsigned short* qkvsb = wsu;                           // [N,512] bf16
  unsigned short* out2b = wsu + (size_t)NN * 512;        // [N,128] bf16
  int* csr_src = (int*)(out2b + (size_t)NN * DD);        // NE
  int* rowptr  = csr_src + NE;                           // N+1
  int* cnt     = rowptr + NN + 1;                        // N
  int* part    = cnt + NN;                               // 391
  int* partx   = part + 512;                             // 512
  size_t woff = (size_t)((partx + 512) - (int*)d_ws);
  woff = (woff + 3) & ~(size_t)3;
  unsigned short* Wqkvs = (unsigned short*)((int*)d_ws + woff);  // [512,128]
  unsigned short* Wob   = Wqkvs + 512 * DD;                      // [128,128]
  unsigned short* W1b   = Wob + DD * DD;                         // [512,128]
  unsigned short* W2b   = W1b + (size_t)HIDD * DD;               // [128,512]
  float* bias512        = (float*)(W2b + (size_t)DD * HIDD);

  float* outf = (float*)d_out;

  const int GX = (NN + 127) / 128;  // 782
  const int GB = (NN + 255) / 256;  // 391
  dim3 blk(256), blk5(512);

  // weights/biases cast+pack + cnt zero (one launch)
  k_castw<<<dim3(600), blk, 0, stream>>>(Wq, Wk, Wv, Wsk, Wo, W1, W2, bq, bk, bv, bsk,
                                         Wqkvs, Wob, W1b, W2b, bias512, cnt);

  // CSR build
  k_count<<<dim3(1954), blk, 0, stream>>>(ei, cnt);
  k_scan1<<<dim3(391), blk, 0, stream>>>(cnt, rowptr, part);
  k_scan2<<<dim3(1), dim3(512), 0, stream>>>(part, partx);
  k_scan3<<<dim3(391), blk, 0, stream>>>(rowptr, partx, cnt);
  k_scatter<<<dim3(1954), blk, 0, stream>>>(ei, cnt, csr_src);

  // fused q|k|v|skip projection: x fp32 -> qkvsb bf16 [N,512]
  k_qkvs<<<dim3(GB), blk5, 0, stream>>>(x, Wqkvs, bias512, qkvsb);

  // single-pass attention (conv lands in skip slot)
  k_attn<<<dim3(12500), blk, 0, stream>>>(csr_src, rowptr, qkvsb);

  // out projection (A = conv slot, lda=512) + x residual + LN1 -> out2b bf16
  k_gemm_ln1<<<dim3(GX), blk, 0, stream>>>(qkvsb + 384, x, Wob, bo, l1w, l1b, out2b);

  // fused FFN (+ residual out2b + LN2) -> d_out fp32; hid never hits HBM
  k_ffn_fused<<<dim3(GX), blk, 0, stream>>>(out2b, W1b, b1, W2b, b2, l2w, l2b, outf);
}

// Round 19
// 268.001 us; speedup vs baseline: 1.1300x; 1.1300x over previous
//
#include <hip/hip_runtime.h>

#define NN   100000
#define NE   500000
#define DD   128
#define HH   4
#define HIDD 512
#define EPSF 1e-5f

typedef __bf16 bf16x8 __attribute__((ext_vector_type(8)));
typedef float  f32x4  __attribute__((ext_vector_type(4)));
typedef unsigned short u16x8 __attribute__((ext_vector_type(8)));

__device__ __forceinline__ unsigned short f2b(float f) {
  unsigned u = __float_as_uint(f);
  unsigned r = (u + 0x7FFFu + ((u >> 16) & 1)) >> 16;
  return (unsigned short)r;
}
__device__ __forceinline__ float b2f(unsigned short s) {
  return __uint_as_float(((unsigned)s) << 16);
}

#define GLOAD16(ldsp, gp) __builtin_amdgcn_global_load_lds(                      \
    (const __attribute__((address_space(1))) void*)(gp),                         \
    (__attribute__((address_space(3))) void*)(ldsp), 16, 0, 0)

// stage a 128x128 bf16 tile: linear LDS dest, inverse-swizzled global source.
// read side uses 16B slot (c16 ^ (row&15)).
template <int NT>
__device__ __forceinline__ void stage_tile(unsigned short* lds, const unsigned short* g,
                                           int ldg, int t) {
  const int w = t >> 6, l = t & 63;
#pragma unroll
  for (int i = 0; i < 2048 / NT; i++) {
    const int chunk0 = i * NT + w * 64;   // wave-uniform
    const int chunk = chunk0 + l;
    const int row = chunk >> 4, c16 = chunk & 15;
    const int gslot = c16 ^ (row & 15);
    GLOAD16(lds + (size_t)chunk0 * 8, g + (size_t)row * ldg + gslot * 8);
  }
}

// weight casts + bias pack + cnt zeroing in ONE launch (600 blocks)
__global__ void k_castw(const float* __restrict__ Wq, const float* __restrict__ Wk,
                        const float* __restrict__ Wv, const float* __restrict__ Wsk,
                        const float* __restrict__ Wo, const float* __restrict__ W1,
                        const float* __restrict__ W2,
                        const float* __restrict__ bq, const float* __restrict__ bk,
                        const float* __restrict__ bv, const float* __restrict__ bs,
                        unsigned short* __restrict__ Wqkvs, unsigned short* __restrict__ Wob,
                        unsigned short* __restrict__ W1b, unsigned short* __restrict__ W2b,
                        float* __restrict__ bias512, int* __restrict__ cnt) {
  int i = blockIdx.x * 256 + threadIdx.x;
  if (i < 53248) {
    int e = i * 4;
    const float* src; unsigned short* dst; int off;
    if (e < 65536) {
      int seg = e >> 14;
      const float* s4[4] = {Wq, Wk, Wv, Wsk};
      src = s4[seg]; dst = Wqkvs + (seg << 14); off = e & 16383;
    } else if (e < 81920) { src = Wo;  dst = Wob; off = e - 65536; }
    else if (e < 147456)  { src = W1;  dst = W1b; off = e - 81920; }
    else                  { src = W2;  dst = W2b; off = e - 147456; }
    float4 v = *(const float4*)&src[off];
    ushort4 o; o.x = f2b(v.x); o.y = f2b(v.y); o.z = f2b(v.z); o.w = f2b(v.w);
    *(ushort4*)&dst[off] = o;
  } else if (i < 53376) {
    int b4 = (i - 53248) * 4;
    const float* srcs[4] = {bq, bk, bv, bs};
#pragma unroll
    for (int j = 0; j < 4; j++) {
      int idx = b4 + j;
      bias512[idx] = srcs[idx >> 7][idx & 127];
    }
  } else if (i >= 53504) {
    int idx = i - 53504;
    if (idx < NN) cnt[idx] = 0;
  }
}

// ---------------- CSR build ----------------
__global__ void k_count(const int* __restrict__ ei, int* __restrict__ cnt) {
  int e = blockIdx.x * 256 + threadIdx.x;
  if (e < NE) atomicAdd(&cnt[ei[NE + e]], 1);
}
__global__ void k_scan1(const int* __restrict__ cnt, int* __restrict__ rowptr, int* __restrict__ part) {
  __shared__ int sh[256];
  int i = blockIdx.x * 256 + threadIdx.x;
  int v = (i < NN) ? cnt[i] : 0;
  sh[threadIdx.x] = v; __syncthreads();
  for (int off = 1; off < 256; off <<= 1) {
    int t = (threadIdx.x >= off) ? sh[threadIdx.x - off] : 0;
    __syncthreads();
    sh[threadIdx.x] += t;
    __syncthreads();
  }
  if (i < NN) rowptr[i] = sh[threadIdx.x] - v;  // exclusive
  if (threadIdx.x == 255) part[blockIdx.x] = sh[255];
}
__global__ void k_scan2(const int* __restrict__ part, int* __restrict__ partx) {
  __shared__ int sh[512];
  int t = threadIdx.x;
  int v = (t < 391) ? part[t] : 0;
  sh[t] = v; __syncthreads();
  for (int off = 1; off < 512; off <<= 1) {
    int u = (t >= off) ? sh[t - off] : 0;
    __syncthreads();
    sh[t] += u;
    __syncthreads();
  }
  partx[t] = sh[t] - v;
}
__global__ void k_scan3(int* __restrict__ rowptr, const int* __restrict__ partx, int* __restrict__ cnt) {
  int i = blockIdx.x * 256 + threadIdx.x;
  if (i < NN) {
    int r = rowptr[i] + partx[i >> 8];
    rowptr[i] = r;
    cnt[i] = r;
  }
  if (i == 0) rowptr[NN] = NE;
}
__global__ void k_scatter(const int* __restrict__ ei, int* __restrict__ cnt, int* __restrict__ csr_src) {
  int e = blockIdx.x * 256 + threadIdx.x;
  if (e >= NE) return;
  int d = ei[NE + e];
  int pos = atomicAdd(&cnt[d], 1);
  csr_src[pos] = ei[e];
}

#define LOADA(dst, Aptr, LDA_)                                                   \
  _Pragma("unroll") for (int ks = 0; ks < 4; ks++)                               \
    _Pragma("unroll") for (int rt = 0; rt < 2; rt++) {                           \
      const int row_ = n0 + rt * 16 + lq;                                        \
      bf16x8 zz = {};                                                            \
      dst[ks][rt] = (row_ < NN)                                                  \
          ? *(const bf16x8*)&(Aptr)[(size_t)row_ * (LDA_) + ks * 32 + hq * 8]    \
          : zz;                                                                  \
    }

#define LOADA_F32(dst, Xp)                                                       \
  _Pragma("unroll") for (int ks = 0; ks < 4; ks++)                               \
    _Pragma("unroll") for (int rt = 0; rt < 2; rt++) {                           \
      const int row_ = n0 + rt * 16 + lq;                                        \
      u16x8 tmp = {};                                                            \
      if (row_ < NN) {                                                           \
        const float* p = (Xp) + (size_t)row_ * 128 + ks * 32 + hq * 8;           \
        float4 f0 = *(const float4*)p, f1 = *(const float4*)(p + 4);             \
        tmp[0]=f2b(f0.x); tmp[1]=f2b(f0.y); tmp[2]=f2b(f0.z); tmp[3]=f2b(f0.w);  \
        tmp[4]=f2b(f1.x); tmp[5]=f2b(f1.y); tmp[6]=f2b(f1.z); tmp[7]=f2b(f1.w);  \
      }                                                                          \
      dst[ks][rt] = *(bf16x8*)&tmp;                                              \
    }

#define MFMA_PHASE(WS, AF, ACC)                                                  \
  _Pragma("unroll") for (int ks = 0; ks < 4; ks++) {                             \
    bf16x8 bb[8];                                                                \
    const int c16_ = ks * 4 + hq;                                                \
    _Pragma("unroll") for (int ct = 0; ct < 8; ct++) {                           \
      const int row_ = ct * 16 + lq;                                             \
      bb[ct] = *(const bf16x8*)&WS[row_ * 128 + ((c16_ ^ lq) * 8)];              \
    }                                                                            \
    _Pragma("unroll") for (int rt = 0; rt < 2; rt++)                             \
      _Pragma("unroll") for (int ct = 0; ct < 8; ct++)                           \
        ACC[rt][ct] = __builtin_amdgcn_mfma_f32_16x16x32_bf16(bb[ct], AF[ks][rt], ACC[rt][ct], 0, 0, 0); \
  }

// ---------------- qkvs: x fp32 -> qkvsb bf16 [N,512]; 256 rows/block, dbuf W ----------------
__global__ __launch_bounds__(512, 2) void k_qkvs(const float* __restrict__ x,
                                                 const unsigned short* __restrict__ W,
                                                 const float* __restrict__ bias,
                                                 unsigned short* __restrict__ outB) {
  __shared__ __align__(16) unsigned short WsA[128 * 128];
  __shared__ __align__(16) unsigned short WsB[128 * 128];
  const int t = threadIdx.x;
  const int w = t >> 6, l = t & 63;
  const int n0 = blockIdx.x * 256 + w * 32;
  const int lq = l & 15, hq = l >> 4;

  bf16x8 af[4][2];
  LOADA_F32(af, x);
  stage_tile<512>(WsA, W, 128, t);
  __syncthreads();
#pragma unroll
  for (int cg = 0; cg < 4; ++cg) {
    unsigned short* cur = (cg & 1) ? WsB : WsA;
    unsigned short* nxt = (cg & 1) ? WsA : WsB;
    if (cg < 3) stage_tile<512>(nxt, W + (size_t)(cg + 1) * 128 * 128, 128, t);
    f32x4 acc[2][8] = {};
    MFMA_PHASE(cur, af, acc)
#pragma unroll
    for (int rt = 0; rt < 2; rt++) {
      const int row = n0 + rt * 16 + lq;
      if (row < NN) {
#pragma unroll
        for (int ct = 0; ct < 8; ct++) {
          const int col = cg * 128 + ct * 16 + hq * 4;
          const float4 bs = *(const float4*)&bias[col];
          ushort4 o;
          o.x = f2b(acc[rt][ct][0] + bs.x);
          o.y = f2b(acc[rt][ct][1] + bs.y);
          o.z = f2b(acc[rt][ct][2] + bs.z);
          o.w = f2b(acc[rt][ct][3] + bs.w);
          *(ushort4*)&outB[(size_t)row * 512 + col] = o;
        }
      }
    }
    if (cg < 3) __syncthreads();
  }
}

// ---------------- out-proj GEMM (K=128) + x residual (fp32) + LN1 -> out2b bf16 ----------------
__global__ __launch_bounds__(256, 4) void k_gemm_ln1(const unsigned short* __restrict__ A,
                                                     const float* __restrict__ x,
                                                     const unsigned short* __restrict__ W,
                                                     const float* __restrict__ bias,
                                                     const float* __restrict__ lw,
                                                     const float* __restrict__ lb,
                                                     unsigned short* __restrict__ outB) {
  __shared__ __align__(16) unsigned short Ws[128 * 128];
  const int t = threadIdx.x;
  const int w = t >> 6, l = t & 63;
  const int n0 = blockIdx.x * 128 + w * 32;
  const int lq = l & 15, hq = l >> 4;

  bf16x8 af[4][2];
  LOADA(af, A, 512);
  stage_tile<256>(Ws, W, 128, t);
  __syncthreads();
  f32x4 acc[2][8] = {};
  MFMA_PHASE(Ws, af, acc)
#pragma unroll
  for (int rt = 0; rt < 2; rt++) {
    const int row = n0 + rt * 16 + lq;
#pragma unroll
    for (int ct = 0; ct < 8; ct++) {
      const int col = ct * 16 + hq * 4;
      const float4 bs = *(const float4*)&bias[col];
      float4 rv = make_float4(0.f, 0.f, 0.f, 0.f);
      if (row < NN) rv = *(const float4*)&x[(size_t)row * DD + col];
      acc[rt][ct][0] += bs.x + rv.x;
      acc[rt][ct][1] += bs.y + rv.y;
      acc[rt][ct][2] += bs.z + rv.z;
      acc[rt][ct][3] += bs.w + rv.w;
    }
    float s = 0.f;
#pragma unroll
    for (int ct = 0; ct < 8; ct++)
#pragma unroll
      for (int j = 0; j < 4; j++) s += acc[rt][ct][j];
    s += __shfl_xor(s, 16, 64); s += __shfl_xor(s, 32, 64);
    const float mu = s * (1.f / 128.f);
    float vs = 0.f;
#pragma unroll
    for (int ct = 0; ct < 8; ct++)
#pragma unroll
      for (int j = 0; j < 4; j++) { float d = acc[rt][ct][j] - mu; vs += d * d; }
    vs += __shfl_xor(vs, 16, 64); vs += __shfl_xor(vs, 32, 64);
    const float rs = rsqrtf(vs * (1.f / 128.f) + EPSF);
    if (row < NN) {
#pragma unroll
      for (int ct = 0; ct < 8; ct++) {
        const int col = ct * 16 + hq * 4;
        const float4 lw4 = *(const float4*)&lw[col];
        const float4 lb4 = *(const float4*)&lb[col];
        ushort4 o;
        o.x = f2b((acc[rt][ct][0] - mu) * rs * lw4.x + lb4.x);
        o.y = f2b((acc[rt][ct][1] - mu) * rs * lw4.y + lb4.y);
        o.z = f2b((acc[rt][ct][2] - mu) * rs * lw4.z + lb4.z);
        o.w = f2b((acc[rt][ct][3] - mu) * rs * lw4.w + lb4.w);
        *(ushort4*)&outB[(size_t)row * DD + col] = o;
      }
    }
  }
}

// ---------------- fused FFN (R14-exact, (256,2)); W2 stage hidden under Hs-write ----------------
__global__ __launch_bounds__(256, 2) void k_ffn_fused(const unsigned short* __restrict__ A,
                                                      const unsigned short* __restrict__ W1,
                                                      const float* __restrict__ b1,
                                                      const unsigned short* __restrict__ W2,
                                                      const float* __restrict__ b2,
                                                      const float* __restrict__ lw,
                                                      const float* __restrict__ lb,
                                                      float* __restrict__ outF) {
  __shared__ __align__(16) unsigned short Ws[128 * 128];
  __shared__ __align__(16) unsigned short Hs[128 * 128];
  const int t = threadIdx.x;
  const int w = t >> 6, l = t & 63;
  const int n0 = blockIdx.x * 128 + w * 32;
  const int lq = l & 15, hq = l >> 4;
  const int lrow = w * 32;

  bf16x8 af[4][2];
  LOADA(af, A, 128);

  f32x4 acc2[2][8] = {};
#pragma unroll 1
  for (int cg = 0; cg < 4; ++cg) {
    if (cg) __syncthreads();              // prev MFMA2 done reading Ws & Hs
    stage_tile<256>(Ws, W1 + (size_t)cg * 128 * 128, 128, t);
    __syncthreads();                      // W1[cg] ready
    f32x4 acc1[2][8] = {};
    MFMA_PHASE(Ws, af, acc1)
    __syncthreads();                      // all W1 reads done
    stage_tile<256>(Ws, W2 + (size_t)cg * 128, 512, t);  // latency hides under Hs-write
#pragma unroll
    for (int rt = 0; rt < 2; rt++) {
      const int row = lrow + rt * 16 + lq;
#pragma unroll
      for (int ct = 0; ct < 8; ct++) {
        const int col = ct * 16 + hq * 4;
        const float4 bs = *(const float4*)&b1[cg * 128 + col];
        ushort4 o;
        o.x = f2b(fmaxf(acc1[rt][ct][0] + bs.x, 0.f));
        o.y = f2b(fmaxf(acc1[rt][ct][1] + bs.y, 0.f));
        o.z = f2b(fmaxf(acc1[rt][ct][2] + bs.z, 0.f));
        o.w = f2b(fmaxf(acc1[rt][ct][3] + bs.w, 0.f));
        *(ushort4*)&Hs[row * 128 + (((col >> 3) ^ lq) * 8) + (col & 7)] = o;
      }
    }
    __syncthreads();                      // W2 ready + Hs visible
#pragma unroll
    for (int ks = 0; ks < 4; ks++) {
      bf16x8 bb[8];
      const int c16_ = ks * 4 + hq;
#pragma unroll
      for (int ct = 0; ct < 8; ct++) {
        const int row_ = ct * 16 + lq;
        bb[ct] = *(const bf16x8*)&Ws[row_ * 128 + ((c16_ ^ lq) * 8)];
      }
      bf16x8 h[2];
#pragma unroll
      for (int rt = 0; rt < 2; rt++)
        h[rt] = *(const bf16x8*)&Hs[(lrow + rt * 16 + lq) * 128 + ((c16_ ^ lq) * 8)];
#pragma unroll
      for (int rt = 0; rt < 2; rt++)
#pragma unroll
        for (int ct = 0; ct < 8; ct++)
          acc2[rt][ct] = __builtin_amdgcn_mfma_f32_16x16x32_bf16(bb[ct], h[rt], acc2[rt][ct], 0, 0, 0);
    }
  }

  // epilogue: + b2 + out2b residual + LN2 -> fp32 d_out
#pragma unroll
  for (int rt = 0; rt < 2; rt++) {
    const int row = n0 + rt * 16 + lq;
#pragma unroll
    for (int ct = 0; ct < 8; ct++) {
      const int col = ct * 16 + hq * 4;
      const float4 bs = *(const float4*)&b2[col];
      ushort4 rv = make_ushort4(0, 0, 0, 0);
      if (row < NN) rv = *(const ushort4*)&A[(size_t)row * DD + col];
      acc2[rt][ct][0] += bs.x + b2f(rv.x);
      acc2[rt][ct][1] += bs.y + b2f(rv.y);
      acc2[rt][ct][2] += bs.z + b2f(rv.z);
      acc2[rt][ct][3] += bs.w + b2f(rv.w);
    }
    float s = 0.f;
#pragma unroll
    for (int ct = 0; ct < 8; ct++)
#pragma unroll
      for (int j = 0; j < 4; j++) s += acc2[rt][ct][j];
    s += __shfl_xor(s, 16, 64); s += __shfl_xor(s, 32, 64);
    const float mu = s * (1.f / 128.f);
    float vs = 0.f;
#pragma unroll
    for (int ct = 0; ct < 8; ct++)
#pragma unroll
      for (int j = 0; j < 4; j++) { float d = acc2[rt][ct][j] - mu; vs += d * d; }
    vs += __shfl_xor(vs, 16, 64); vs += __shfl_xor(vs, 32, 64);
    const float rs = rsqrtf(vs * (1.f / 128.f) + EPSF);
    if (row < NN) {
#pragma unroll
      for (int ct = 0; ct < 8; ct++) {
        const int col = ct * 16 + hq * 4;
        const float4 lw4 = *(const float4*)&lw[col];
        const float4 lb4 = *(const float4*)&lb[col];
        float4 o;
        o.x = (acc2[rt][ct][0] - mu) * rs * lw4.x + lb4.x;
        o.y = (acc2[rt][ct][1] - mu) * rs * lw4.y + lb4.y;
        o.z = (acc2[rt][ct][2] - mu) * rs * lw4.z + lb4.z;
        o.w = (acc2[rt][ct][3] - mu) * rs * lw4.w + lb4.w;
        *(float4*)&outF[(size_t)row * DD + col] = o;
      }
    }
  }
}

// ---------------- single-pass fused attention (R14-exact: ushort4 loads, unroll x4) ----------------
__global__ __launch_bounds__(256) void k_attn(const int* __restrict__ csr_src,
                                              const int* __restrict__ rowptr,
                                              unsigned short* qkvsb) {
  const int l = threadIdx.x & 31;
  const int node = blockIdx.x * 8 + (threadIdx.x >> 5);
  const int row0 = rowptr[node], row1 = rowptr[node + 1];
  ushort4 qu = *(const ushort4*)&qkvsb[(size_t)node * 512 + l * 4];
  const float qx = b2f(qu.x), qy = b2f(qu.y), qz = b2f(qu.z), qw = b2f(qu.w);
  float ax = 0.f, ay = 0.f, az = 0.f, aw = 0.f, z = 0.f;
  int p = row0;
  for (; p + 4 <= row1; p += 4) {
    int s0 = csr_src[p], s1 = csr_src[p + 1], s2 = csr_src[p + 2], s3 = csr_src[p + 3];
    const unsigned short* g0 = &qkvsb[(size_t)s0 * 512 + l * 4];
    const unsigned short* g1 = &qkvsb[(size_t)s1 * 512 + l * 4];
    const unsigned short* g2 = &qkvsb[(size_t)s2 * 512 + l * 4];
    const unsigned short* g3 = &qkvsb[(size_t)s3 * 512 + l * 4];
    ushort4 k0 = *(const ushort4*)(g0 + 128), v0 = *(const ushort4*)(g0 + 256);
    ushort4 k1 = *(const ushort4*)(g1 + 128), v1 = *(const ushort4*)(g1 + 256);
    ushort4 k2 = *(const ushort4*)(g2 + 128), v2 = *(const ushort4*)(g2 + 256);
    ushort4 k3 = *(const ushort4*)(g3 + 128), v3 = *(const ushort4*)(g3 + 256);
    float d0 = qx * b2f(k0.x) + qy * b2f(k0.y) + qz * b2f(k0.z) + qw * b2f(k0.w);
    float d1 = qx * b2f(k1.x) + qy * b2f(k1.y) + qz * b2f(k1.z) + qw * b2f(k1.w);
    float d2 = qx * b2f(k2.x) + qy * b2f(k2.y) + qz * b2f(k2.z) + qw * b2f(k2.w);
    float d3 = qx * b2f(k3.x) + qy * b2f(k3.y) + qz * b2f(k3.z) + qw * b2f(k3.w);
    d0 += __shfl_xor(d0, 1, 32); d1 += __shfl_xor(d1, 1, 32);
    d2 += __shfl_xor(d2, 1, 32); d3 += __shfl_xor(d3, 1, 32);
    d0 += __shfl_xor(d0, 2, 32); d1 += __shfl_xor(d1, 2, 32);
    d2 += __shfl_xor(d2, 2, 32); d3 += __shfl_xor(d3, 2, 32);
    d0 += __shfl_xor(d0, 4, 32); d1 += __shfl_xor(d1, 4, 32);
    d2 += __shfl_xor(d2, 4, 32); d3 += __shfl_xor(d3, 4, 32);
    float e0 = __expf(d0 * 0.17677669529663687f);
    float e1 = __expf(d1 * 0.17677669529663687f);
    float e2 = __expf(d2 * 0.17677669529663687f);
    float e3 = __expf(d3 * 0.17677669529663687f);
    z += (e0 + e1) + (e2 + e3);
    ax += e0 * b2f(v0.x) + e1 * b2f(v1.x) + e2 * b2f(v2.x) + e3 * b2f(v3.x);
    ay += e0 * b2f(v0.y) + e1 * b2f(v1.y) + e2 * b2f(v2.y) + e3 * b2f(v3.y);
    az += e0 * b2f(v0.z) + e1 * b2f(v1.z) + e2 * b2f(v2.z) + e3 * b2f(v3.z);
    aw += e0 * b2f(v0.w) + e1 * b2f(v1.w) + e2 * b2f(v2.w) + e3 * b2f(v3.w);
  }
  for (; p < row1; ++p) {
    int s = csr_src[p];
    const unsigned short* base = &qkvsb[(size_t)s * 512 + l * 4];
    ushort4 kr = *(const ushort4*)(base + 128);
    ushort4 vr = *(const ushort4*)(base + 256);
    float d = qx * b2f(kr.x) + qy * b2f(kr.y) + qz * b2f(kr.z) + qw * b2f(kr.w);
    d += __shfl_xor(d, 1, 32);
    d += __shfl_xor(d, 2, 32);
    d += __shfl_xor(d, 4, 32);
    float e = __expf(d * 0.17677669529663687f);
    z += e;
    ax += e * b2f(vr.x); ay += e * b2f(vr.y);
    az += e * b2f(vr.z); aw += e * b2f(vr.w);
  }
  const float rz = (z > 0.f) ? (1.f / z) : 0.f;
  ushort4 su = *(const ushort4*)&qkvsb[(size_t)node * 512 + 384 + l * 4];
  ushort4 o;
  o.x = f2b(b2f(su.x) + ax * rz);
  o.y = f2b(b2f(su.y) + ay * rz);
  o.z = f2b(b2f(su.z) + az * rz);
  o.w = f2b(b2f(su.w) + aw * rz);
  *(ushort4*)&qkvsb[(size_t)node * 512 + 384 + l * 4] = o;
}

extern "C" void kernel_launch(void* const* d_in, const int* in_sizes, int n_in,
                              void* d_out, int out_size, void* d_ws, size_t ws_size,
                              hipStream_t stream) {
  const float* x   = (const float*)d_in[0];
  const int*   ei  = (const int*)d_in[1];
  const float* Wq  = (const float*)d_in[2];
  const float* bq  = (const float*)d_in[3];
  const float* Wk  = (const float*)d_in[4];
  const float* bk  = (const float*)d_in[5];
  const float* Wv  = (const float*)d_in[6];
  const float* bv  = (const float*)d_in[7];
  const float* Wsk = (const float*)d_in[8];
  const float* bsk = (const float*)d_in[9];
  const float* Wo  = (const float*)d_in[10];
  const float* bo  = (const float*)d_in[11];
  const float* l1w = (const float*)d_in[12];
  const float* l1b = (const float*)d_in[13];
  const float* l2w = (const float*)d_in[14];
  const float* l2b = (const float*)d_in[15];
  const float* W1  = (const float*)d_in[16];
  const float* b1  = (const float*)d_in[17];
  const float* W2  = (const float*)d_in[18];
  const float* b2  = (const float*)d_in[19];

  unsigned short* wsu = (unsigned short*)d_ws;
  unsigned short* qkvsb = wsu;                           // [N,512] bf16
  unsigned short* out2b = wsu + (size_t)NN * 512;        // [N,128] bf16
  int* csr_src = (int*)(out2b + (size_t)NN * DD);        // NE
  int* rowptr  = csr_src + NE;                           // N+1
  int* cnt     = rowptr + NN + 1;                        // N
  int* part    = cnt + NN;                               // 391
  int* partx   = part + 512;                             // 512
  size_t woff = (size_t)((partx + 512) - (int*)d_ws);
  woff = (woff + 3) & ~(size_t)3;
  unsigned short* Wqkvs = (unsigned short*)((int*)d_ws + woff);  // [512,128]
  unsigned short* Wob   = Wqkvs + 512 * DD;                      // [128,128]
  unsigned short* W1b   = Wob + DD * DD;                         // [512,128]
  unsigned short* W2b   = W1b + (size_t)HIDD * DD;               // [128,512]
  float* bias512        = (float*)(W2b + (size_t)DD * HIDD);

  float* outf = (float*)d_out;

  const int GX = (NN + 127) / 128;  // 782
  const int GB = (NN + 255) / 256;  // 391
  dim3 blk(256), blk5(512);

  // weights/biases cast+pack + cnt zero (one launch)
  k_castw<<<dim3(600), blk, 0, stream>>>(Wq, Wk, Wv, Wsk, Wo, W1, W2, bq, bk, bv, bsk,
                                         Wqkvs, Wob, W1b, W2b, bias512, cnt);

  // CSR build
  k_count<<<dim3(1954), blk, 0, stream>>>(ei, cnt);
  k_scan1<<<dim3(391), blk, 0, stream>>>(cnt, rowptr, part);
  k_scan2<<<dim3(1), dim3(512), 0, stream>>>(part, partx);
  k_scan3<<<dim3(391), blk, 0, stream>>>(rowptr, partx, cnt);
  k_scatter<<<dim3(1954), blk, 0, stream>>>(ei, cnt, csr_src);

  // fused q|k|v|skip projection: x fp32 -> qkvsb bf16 [N,512]
  k_qkvs<<<dim3(GB), blk5, 0, stream>>>(x, Wqkvs, bias512, qkvsb);

  // single-pass attention (conv lands in skip slot)
  k_attn<<<dim3(12500), blk, 0, stream>>>(csr_src, rowptr, qkvsb);

  // out projection (A = conv slot, lda=512) + x residual + LN1 -> out2b bf16
  k_gemm_ln1<<<dim3(GX), blk, 0, stream>>>(qkvsb + 384, x, Wob, bo, l1w, l1b, out2b);

  // fused FFN (+ residual out2b + LN2) -> d_out fp32; hid never hits HBM
  k_ffn_fused<<<dim3(GX), blk, 0, stream>>>(out2b, W1b, b1, W2b, b2, l2w, l2b, outf);
}